// Round 10
// baseline (38.497 us; speedup 1.0000x reference)
//
#include <hip/hip_runtime.h>
#include <hip/hip_bf16.h>

#define NJ 24
#define TLEN 25000
#define NB 4
#define CHUNKS 20
#define NWPB (CHUNKS*4)           // waves per (b,j) = 80
#define NIT32 ((TLEN+31)/32)      // 782 tiles of 32 cols

typedef short short8 __attribute__((ext_vector_type(8)));
typedef short s16x2 __attribute__((ext_vector_type(2)));
typedef float f32x16 __attribute__((ext_vector_type(16)));

union FragU { unsigned u[4]; short8 s; };

// Fast f32x2 -> packed bf16x2, round-half-up: (bits + 0x8000) then take hi16
// of each via one v_perm_b32. 3 VALU ops. Differs from RTNE only at exact
// half-ulp ties; cannot produce NaN/Inf from finite inputs. NOTE: do NOT use
// inline-asm v_cvt_pk_bf16_f32 — it NaN'd on this toolchain (R5).
__device__ __forceinline__ unsigned pack2(float a, float b){
    unsigned ua = __float_as_uint(a) + 0x8000u;
    unsigned ub = __float_as_uint(b) + 0x8000u;
    return __builtin_amdgcn_perm(ub, ua, 0x07060302u);
}
__device__ __forceinline__ float bflo(unsigned u){
    union { unsigned v; float f; } t; t.v = u << 16; return t.f;
}

// packed bf16 relu: bf16 bit patterns compare correctly as signed i16;
// max_i16(x, 0) maps any negative bf16 to +0.0 and keeps positives.
__device__ __forceinline__ unsigned pkrelu(unsigned x){
    union { unsigned u; s16x2 v; } a, r;
    a.u = x;
    s16x2 z; z[0] = 0; z[1] = 0;
    r.v = __builtin_elementwise_max(a.v, z);
    return r.u;
}

__device__ __forceinline__ f32x16 mfma(const FragU &a, const FragU &b, f32x16 c){
    return __builtin_amdgcn_mfma_f32_32x32x16_bf16(a.s, b.s, c, 0, 0, 0);
}

__device__ __forceinline__ FragU mk1(unsigned w){
    FragU f; f.u[0] = w; f.u[1] = 0; f.u[2] = 0; f.u[3] = 0; return f;
}

// round-to-bf16 then packed relu (== relu then round); zero-shuffle layer
// chaining: channel labels of next layer are pi-permuted so regs 0..7 -> frag
// k0, 8..15 -> frag k1, compensated in the weight gather below.
__device__ __forceinline__ void relu_pack(const f32x16 &acc, FragU &k0, FragU &k1){
    unsigned w[8];
    #pragma unroll
    for (int i = 0; i < 8; ++i) w[i] = pkrelu(pack2(acc[2*i], acc[2*i+1]));
    k0.u[0]=w[0]; k0.u[1]=w[1]; k0.u[2]=w[2]; k0.u[3]=w[3];
    k1.u[0]=w[4]; k1.u[1]=w[5]; k1.u[2]=w[6]; k1.u[3]=w[7];
}

// launch_bounds(256,2): DO NOT raise the 2nd arg — (256,4) caps the unified
// VGPR/AGPR budget at 128/wave, regalloc split 64+64 and spilled (R2: FETCH
// 303MB / WRITE 184MB scratch traffic, 150us).
// R10: ONE 32-col chain per trip (R9 had two). Halves live accumulator
// state (acc/bAcc/o f32x16 in the unified VGPR/AGPR file) — theory: total
// regs/wave ~160-176 capped residency at ~3 waves/SIMD across R1-R9;
// halving acc -> ~4-5 waves/SIMD fills the ~1100-cyc serial chain.
// (R8 = the inverse experiment: 4 chains raised regs, hurt.)
__global__ __launch_bounds__(256, 2) void ptf_decoder_kernel(
    const float* __restrict__ p,    const float* __restrict__ c,
    const float* __restrict__ Wproj,const float* __restrict__ bproj,
    const float* __restrict__ Wp,   const float* __restrict__ bp,
    const float* __restrict__ W0,   const float* __restrict__ b0,
    const float* __restrict__ W1,   const float* __restrict__ b1,
    const float* __restrict__ W2,   const float* __restrict__ b2,
    const float* __restrict__ Wout, const float* __restrict__ bout,
    float* __restrict__ out)
{
    __shared__ __align__(16) float ldsW[3][32][36];  // padded: 4-way max on b128 gathers
    __shared__ __align__(16) float ldsWp[32][8];
    __shared__ __align__(16) float ldsB[3][32];
    __shared__ __align__(16) float ldsWo[32];

    const int tid = threadIdx.x;
    const int bj  = blockIdx.x % (NB*NJ);
    const int sub = blockIdx.x / (NB*NJ);
    const int b   = bj / NJ;
    const int j   = bj % NJ;

    // ---- stage this joint's weights into LDS (coalesced) ----
    {
        const float* Wl[3] = {W0, W1, W2};
        #pragma unroll
        for (int L = 0; L < 3; ++L) {
            int row = tid >> 3, c4 = tid & 7;           // 256 threads = 32 rows x 8 float4
            float4 v = *reinterpret_cast<const float4*>(Wl[L] + ((size_t)(j*32 + row))*32 + c4*4);
            *reinterpret_cast<float4*>(&ldsW[L][row][c4*4]) = v;
        }
        {
            int row = tid >> 3, i8 = tid & 7;
            // col 7 carries b_p (first-layer bias rides k=7 with input 1.0)
            ldsWp[row][i8] = (i8 < 7) ? Wp[((size_t)(j*32 + row))*7 + i8]
                                      : bp[j*32 + row];
        }
        if      (tid < 32)  ldsB[0][tid]      = b0[j*32 + tid];
        else if (tid < 64)  ldsB[1][tid-32]   = b1[j*32 + tid-32];
        else if (tid < 96)  ldsB[2][tid-64]   = b2[j*32 + tid-64];
        else if (tid < 128) ldsWo[tid-96]     = Wout[j*32 + tid-96];
    }
    __syncthreads();

    const int lane = tid & 63;
    const int row  = lane & 31;
    const int h    = lane >> 5;

    // ---- per-lane weight fragments (bf16 hi only), pi-permuted k labels ----
    FragU whi[3][2];
    #pragma unroll
    for (int L = 0; L < 3; ++L) {
        #pragma unroll
        for (int kh = 0; kh < 2; ++kh) {
            const int g  = kh*2 + h;                 // k-group
            const int cA = (g >> 1)*4 + (g & 1);     // chunk pairs {0,2},{1,3},{4,6},{5,7}
            const float* base = &ldsW[L][row][0];
            float4 x = *reinterpret_cast<const float4*>(base + cA*4);
            float4 y = *reinterpret_cast<const float4*>(base + (cA+2)*4);
            whi[L][kh].u[0] = pack2(x.x, x.y);
            whi[L][kh].u[1] = pack2(x.z, x.w);
            whi[L][kh].u[2] = pack2(y.x, y.y);
            whi[L][kh].u[3] = pack2(y.z, y.w);
        }
    }
    // output layer as MFMA: wo broadcast to all 32 rows, same pi-compensated
    // column gather as whi -> every D reg holds the full 1x32 dot.
    FragU woF[2];
    #pragma unroll
    for (int kh = 0; kh < 2; ++kh) {
        const int g  = kh*2 + h;
        const int cA = (g >> 1)*4 + (g & 1);
        float4 x = *reinterpret_cast<const float4*>(&ldsWo[cA*4]);
        float4 y = *reinterpret_cast<const float4*>(&ldsWo[(cA+2)*4]);
        woF[kh].u[0] = pack2(x.x, x.y);
        woF[kh].u[1] = pack2(x.z, x.w);
        woF[kh].u[2] = pack2(y.x, y.y);
        woF[kh].u[3] = pack2(y.z, y.w);
    }
    // first layer: bf16 hi only (margin absorbs it — R9 verified 0.0156)
    FragU wphi;
    {
        float4 x = make_float4(0,0,0,0), y = make_float4(0,0,0,0);
        if (lane < 32) {
            x = *reinterpret_cast<const float4*>(&ldsWp[row][0]);
            y = *reinterpret_cast<const float4*>(&ldsWp[row][4]);
        }
        wphi.u[0] = pack2(x.x, x.y);
        wphi.u[1] = pack2(x.z, x.w);
        wphi.u[2] = pack2(y.x, y.y);
        wphi.u[3] = pack2(y.z, y.w);
    }

    // ---- hidden-layer biases as 1-reg A-fragments: k0=hi(b), k1=lo(b) ----
    unsigned biasA[3];
    #pragma unroll
    for (int L = 0; L < 3; ++L) {
        float bl = (h == 0) ? ldsB[L][row] : 0.f;
        unsigned t = pack2(bl, 0.f);
        float res = bl - bflo(t);
        biasA[L] = (h == 0) ? pack2(bl, res) : 0u;
    }
    const unsigned ones2 = (h == 0) ? 0x3f803f80u : 0u;   // {1.0bf16, 1.0bf16}

    // shared zero accumulator C (read-only)
    f32x16 kZero;
    #pragma unroll
    for (int r = 0; r < 16; ++r) kZero[r] = 0.f;

    // ---- c projection: c_proj[o] = dot(c[b], Wproj[j][o]) + bproj ----
    float cacc0, cacc1, cacc2, cacc3;
    {
        const float* cb  = c + (size_t)b*128;
        const float* wpj = Wproj + (size_t)j*4*128;
        float cl = cb[lane], chv = cb[lane + 64];
        cacc0 = cl*wpj[0*128+lane] + chv*wpj[0*128+lane+64];
        cacc1 = cl*wpj[1*128+lane] + chv*wpj[1*128+lane+64];
        cacc2 = cl*wpj[2*128+lane] + chv*wpj[2*128+lane+64];
        cacc3 = cl*wpj[3*128+lane] + chv*wpj[3*128+lane+64];
        #pragma unroll
        for (int off = 32; off >= 1; off >>= 1) {
            cacc0 += __shfl_xor(cacc0, off, 64);
            cacc1 += __shfl_xor(cacc1, off, 64);
            cacc2 += __shfl_xor(cacc2, off, 64);
            cacc3 += __shfl_xor(cacc3, off, 64);
        }
        cacc0 += bproj[j*4+0]; cacc1 += bproj[j*4+1];
        cacc2 += bproj[j*4+2]; cacc3 += bproj[j*4+3];
    }
    const float c0v = (lane < 32) ? cacc0 : 0.f;
    unsigned wc2h = pack2(cacc1, cacc2);
    unsigned wc3h = pack2(cacc3, 1.0f);   // k6=c3, k7=1.0 (bias slot)
    if (lane >= 32) { wc2h = 0; wc3h = 0; }
    const float bo = bout[j];

    // ---- main loop over 32-column tiles (single chain) ----
    const float* pb0 = p + ((size_t)(b*(NJ*3) + j*3 + 0))*TLEN;
    const float* pb1 = pb0 + TLEN;
    const float* pb2 = pb1 + TLEN;
    float* ob = out + ((size_t)(b*NJ + j))*TLEN;

    const int w0idx = sub*4 + (tid >> 6);

    auto loadP = [&](int itx, float&x0, float&x1, float&x2){
        x0=0.f; x1=0.f; x2=0.f;
        if (itx < NIT32 && lane < 32) {
            int t = itx*32 + lane;
            t = t < TLEN ? t : TLEN-1;
            x0 = pb0[t]; x1 = pb1[t]; x2 = pb2[t];
        }
    };

    float a0,a1,a2;
    loadP(w0idx, a0,a1,a2);

    for (int it = w0idx; it < NIT32; it += NWPB) {
        float n0,n1,n2;
        loadP(it + NWPB, n0,n1,n2);   // prefetch next tile

        // input fragment (bf16 hi only); lanes>=32 supply k=8..15 = zero
        FragU fh;
        fh.u[0] = pack2(a0, a1);
        fh.u[1] = pack2(a2, c0v);
        fh.u[2] = wc2h;
        fh.u[3] = wc3h;

        f32x16 acc = mfma(wphi, fh, kZero);

        #pragma unroll
        for (int L = 0; L < 3; ++L) {
            // data-independent bias surface; issues early, overlaps packing
            f32x16 bAcc = mfma(mk1(biasA[L]), mk1(ones2), kZero);
            FragU p0, p1;
            relu_pack(acc, p0, p1);
            acc = mfma(whi[L][0], p0, bAcc);
            acc = mfma(whi[L][1], p1, acc);
        }

        // output layer: relu_pack + broadcast-wo MFMA (D[any reg] = dot)
        FragU q0, q1;
        relu_pack(acc, q0, q1);
        f32x16 o = mfma(woF[0], q0, kZero);
        o = mfma(woF[1], q1, o);

        int t = it*32 + row;
        if (lane < 32 && t < TLEN) ob[t] = o[0] + bo;

        a0=n0; a1=n1; a2=n2;
    }
}

extern "C" void kernel_launch(void* const* d_in, const int* in_sizes, int n_in,
                              void* d_out, int out_size, void* d_ws, size_t ws_size,
                              hipStream_t stream) {
    const float* p     = (const float*)d_in[0];
    // d_in[1] = z (unused by reference)
    const float* c     = (const float*)d_in[2];
    const float* Wproj = (const float*)d_in[3];
    const float* bproj = (const float*)d_in[4];
    const float* Wp    = (const float*)d_in[5];
    const float* bp    = (const float*)d_in[6];
    const float* W0    = (const float*)d_in[7];
    const float* b0    = (const float*)d_in[8];
    const float* W1    = (const float*)d_in[9];
    const float* b1    = (const float*)d_in[10];
    const float* W2    = (const float*)d_in[11];
    const float* b2    = (const float*)d_in[12];
    const float* Wout  = (const float*)d_in[13];
    const float* bout  = (const float*)d_in[14];
    float* out = (float*)d_out;

    dim3 grid(NB*NJ*CHUNKS), block(256);
    ptf_decoder_kernel<<<grid, block, 0, stream>>>(
        p, c, Wproj, bproj, Wp, bp, W0, b0, W1, b1, W2, b2, Wout, bout, out);
}

// Round 11
// 37.394 us; speedup vs baseline: 1.0295x; 1.0295x over previous
//
#include <hip/hip_runtime.h>
#include <hip/hip_bf16.h>

#define NJ 24
#define TLEN 25000
#define NB 4
#define CHUNKS 7
#define NWPB (CHUNKS*4)           // waves per (b,j) = 28
#define NGRP ((TLEN+127)/128)     // 196 groups of 128 cols = 28 waves x 7

typedef short short8 __attribute__((ext_vector_type(8)));
typedef short s16x2 __attribute__((ext_vector_type(2)));
typedef float f32x16 __attribute__((ext_vector_type(16)));

union FragU { unsigned u[4]; short8 s; };

// Fast f32x2 -> packed bf16x2, round-half-up: (bits + 0x8000) then take hi16
// of each via one v_perm_b32. 3 VALU ops. Differs from RTNE only at exact
// half-ulp ties; cannot produce NaN/Inf from finite inputs. NOTE: do NOT use
// inline-asm v_cvt_pk_bf16_f32 — it NaN'd on this toolchain (R5).
__device__ __forceinline__ unsigned pack2(float a, float b){
    unsigned ua = __float_as_uint(a) + 0x8000u;
    unsigned ub = __float_as_uint(b) + 0x8000u;
    return __builtin_amdgcn_perm(ub, ua, 0x07060302u);
}
__device__ __forceinline__ float bflo(unsigned u){
    union { unsigned v; float f; } t; t.v = u << 16; return t.f;
}

// packed bf16 relu: bf16 bit patterns compare correctly as signed i16;
// max_i16(x, 0) maps any negative bf16 to +0.0 and keeps positives.
__device__ __forceinline__ unsigned pkrelu(unsigned x){
    union { unsigned u; s16x2 v; } a, r;
    a.u = x;
    s16x2 z; z[0] = 0; z[1] = 0;
    r.v = __builtin_elementwise_max(a.v, z);
    return r.u;
}

__device__ __forceinline__ f32x16 mfma(const FragU &a, const FragU &b, f32x16 c){
    return __builtin_amdgcn_mfma_f32_32x32x16_bf16(a.s, b.s, c, 0, 0, 0);
}

__device__ __forceinline__ FragU mk1(unsigned w){
    FragU f; f.u[0] = w; f.u[1] = 0; f.u[2] = 0; f.u[3] = 0; return f;
}

// round-to-bf16 then packed relu (== relu then round); zero-shuffle layer
// chaining: channel labels of next layer are pi-permuted so regs 0..7 -> frag
// k0, 8..15 -> frag k1, compensated in the weight gather below.
__device__ __forceinline__ void relu_pack(const f32x16 &acc, FragU &k0, FragU &k1){
    unsigned w[8];
    #pragma unroll
    for (int i = 0; i < 8; ++i) w[i] = pkrelu(pack2(acc[2*i], acc[2*i+1]));
    k0.u[0]=w[0]; k0.u[1]=w[1]; k0.u[2]=w[2]; k0.u[3]=w[3];
    k1.u[0]=w[4]; k1.u[1]=w[5]; k1.u[2]=w[6]; k1.u[3]=w[7];
}

// launch_bounds(256,2): DO NOT raise the 2nd arg — (256,4) spilled (R2).
// R11: stride-4 column interleave. A tile's 32 cols are t = base+4*col+k;
// one float4/stream/lane = 4 tiles, component k = tile k, no shuffles.
// Output of 4 tiles = contiguous float4 store. Amortizes the ~900cyc cold
// HBM load latency over 4 serial tile-chains (~2000cyc compute) — R9/R10
// fit wall = trips x ~3100cyc/residency regardless of trip size => the
// stall is exposed per-trip load latency, not issue or regs (R10: occ 31%,
// VGPR 52, still 38.5us). Grid 672 = single co-resident round, 7 groups
// per wave exactly, zero imbalance.
__global__ __launch_bounds__(256, 2) void ptf_decoder_kernel(
    const float* __restrict__ p,    const float* __restrict__ c,
    const float* __restrict__ Wproj,const float* __restrict__ bproj,
    const float* __restrict__ Wp,   const float* __restrict__ bp,
    const float* __restrict__ W0,   const float* __restrict__ b0,
    const float* __restrict__ W1,   const float* __restrict__ b1,
    const float* __restrict__ W2,   const float* __restrict__ b2,
    const float* __restrict__ Wout, const float* __restrict__ bout,
    float* __restrict__ out)
{
    __shared__ __align__(16) float ldsW[3][32][36];  // padded: 4-way max on b128 gathers
    __shared__ __align__(16) float ldsWp[32][8];
    __shared__ __align__(16) float ldsB[3][32];
    __shared__ __align__(16) float ldsWo[32];

    const int tid = threadIdx.x;
    const int bj  = blockIdx.x % (NB*NJ);
    const int sub = blockIdx.x / (NB*NJ);
    const int b   = bj / NJ;
    const int j   = bj % NJ;

    // ---- stage this joint's weights into LDS (coalesced) ----
    {
        const float* Wl[3] = {W0, W1, W2};
        #pragma unroll
        for (int L = 0; L < 3; ++L) {
            int row = tid >> 3, c4 = tid & 7;           // 256 threads = 32 rows x 8 float4
            float4 v = *reinterpret_cast<const float4*>(Wl[L] + ((size_t)(j*32 + row))*32 + c4*4);
            *reinterpret_cast<float4*>(&ldsW[L][row][c4*4]) = v;
        }
        {
            int row = tid >> 3, i8 = tid & 7;
            // col 7 carries b_p (first-layer bias rides k=7 with input 1.0)
            ldsWp[row][i8] = (i8 < 7) ? Wp[((size_t)(j*32 + row))*7 + i8]
                                      : bp[j*32 + row];
        }
        if      (tid < 32)  ldsB[0][tid]      = b0[j*32 + tid];
        else if (tid < 64)  ldsB[1][tid-32]   = b1[j*32 + tid-32];
        else if (tid < 96)  ldsB[2][tid-64]   = b2[j*32 + tid-64];
        else if (tid < 128) ldsWo[tid-96]     = Wout[j*32 + tid-96];
    }
    __syncthreads();

    const int lane = tid & 63;
    const int row  = lane & 31;
    const int h    = lane >> 5;

    // ---- per-lane weight fragments (bf16 hi only), pi-permuted k labels ----
    FragU whi[3][2];
    #pragma unroll
    for (int L = 0; L < 3; ++L) {
        #pragma unroll
        for (int kh = 0; kh < 2; ++kh) {
            const int g  = kh*2 + h;                 // k-group
            const int cA = (g >> 1)*4 + (g & 1);     // chunk pairs {0,2},{1,3},{4,6},{5,7}
            const float* base = &ldsW[L][row][0];
            float4 x = *reinterpret_cast<const float4*>(base + cA*4);
            float4 y = *reinterpret_cast<const float4*>(base + (cA+2)*4);
            whi[L][kh].u[0] = pack2(x.x, x.y);
            whi[L][kh].u[1] = pack2(x.z, x.w);
            whi[L][kh].u[2] = pack2(y.x, y.y);
            whi[L][kh].u[3] = pack2(y.z, y.w);
        }
    }
    // output layer as MFMA: wo broadcast to all 32 rows, same pi-compensated
    // column gather as whi -> every D reg holds the full 1x32 dot.
    FragU woF[2];
    #pragma unroll
    for (int kh = 0; kh < 2; ++kh) {
        const int g  = kh*2 + h;
        const int cA = (g >> 1)*4 + (g & 1);
        float4 x = *reinterpret_cast<const float4*>(&ldsWo[cA*4]);
        float4 y = *reinterpret_cast<const float4*>(&ldsWo[(cA+2)*4]);
        woF[kh].u[0] = pack2(x.x, x.y);
        woF[kh].u[1] = pack2(x.z, x.w);
        woF[kh].u[2] = pack2(y.x, y.y);
        woF[kh].u[3] = pack2(y.z, y.w);
    }
    // first layer: bf16 hi only (margin absorbs it — R9/R10 verified 0.0156)
    FragU wphi;
    {
        float4 x = make_float4(0,0,0,0), y = make_float4(0,0,0,0);
        if (lane < 32) {
            x = *reinterpret_cast<const float4*>(&ldsWp[row][0]);
            y = *reinterpret_cast<const float4*>(&ldsWp[row][4]);
        }
        wphi.u[0] = pack2(x.x, x.y);
        wphi.u[1] = pack2(x.z, x.w);
        wphi.u[2] = pack2(y.x, y.y);
        wphi.u[3] = pack2(y.z, y.w);
    }

    // ---- hidden-layer biases as 1-reg A-fragments: k0=hi(b), k1=lo(b) ----
    unsigned biasA[3];
    #pragma unroll
    for (int L = 0; L < 3; ++L) {
        float bl = (h == 0) ? ldsB[L][row] : 0.f;
        unsigned t = pack2(bl, 0.f);
        float res = bl - bflo(t);
        biasA[L] = (h == 0) ? pack2(bl, res) : 0u;
    }
    const unsigned ones2 = (h == 0) ? 0x3f803f80u : 0u;   // {1.0bf16, 1.0bf16}

    // shared zero accumulator C (read-only)
    f32x16 kZero;
    #pragma unroll
    for (int r = 0; r < 16; ++r) kZero[r] = 0.f;

    // ---- c projection: c_proj[o] = dot(c[b], Wproj[j][o]) + bproj ----
    float cacc0, cacc1, cacc2, cacc3;
    {
        const float* cb  = c + (size_t)b*128;
        const float* wpj = Wproj + (size_t)j*4*128;
        float cl = cb[lane], chv = cb[lane + 64];
        cacc0 = cl*wpj[0*128+lane] + chv*wpj[0*128+lane+64];
        cacc1 = cl*wpj[1*128+lane] + chv*wpj[1*128+lane+64];
        cacc2 = cl*wpj[2*128+lane] + chv*wpj[2*128+lane+64];
        cacc3 = cl*wpj[3*128+lane] + chv*wpj[3*128+lane+64];
        #pragma unroll
        for (int off = 32; off >= 1; off >>= 1) {
            cacc0 += __shfl_xor(cacc0, off, 64);
            cacc1 += __shfl_xor(cacc1, off, 64);
            cacc2 += __shfl_xor(cacc2, off, 64);
            cacc3 += __shfl_xor(cacc3, off, 64);
        }
        cacc0 += bproj[j*4+0]; cacc1 += bproj[j*4+1];
        cacc2 += bproj[j*4+2]; cacc3 += bproj[j*4+3];
    }
    const float c0v = (lane < 32) ? cacc0 : 0.f;
    unsigned wc2h = pack2(cacc1, cacc2);
    unsigned wc3h = pack2(cacc3, 1.0f);   // k6=c3, k7=1.0 (bias slot)
    if (lane >= 32) { wc2h = 0; wc3h = 0; }
    const float bo = bout[j];

    // ---- main loop over 128-col groups (4 stride-interleaved 32-col tiles) ----
    const float* pb0 = p + ((size_t)(b*(NJ*3) + j*3 + 0))*TLEN;
    const float* pb1 = pb0 + TLEN;
    const float* pb2 = pb1 + TLEN;
    float* ob = out + ((size_t)(b*NJ + j))*TLEN;

    const int w0idx = sub*4 + (tid >> 6);

    // one float4 per stream: lane r holds t = g*128 + 4r + {0,1,2,3};
    // component k feeds tile k at column r. Clamped loads (always issue,
    // garbage groups/lanes discarded at store) — no per-trip zero/exec cost
    // except the h=0 predicate.
    auto loadG = [&](int gx, float4&x0, float4&x1, float4&x2){
        x0 = make_float4(0,0,0,0);
        x1 = make_float4(0,0,0,0);
        x2 = make_float4(0,0,0,0);
        gx = gx < NGRP ? gx : NGRP-1;
        int t = gx*128 + row*4;
        t = (t + 3 < TLEN) ? t : (TLEN - 4);   // stays 16B-aligned (mult of 4)
        if (lane < 32) {
            x0 = *reinterpret_cast<const float4*>(pb0 + t);
            x1 = *reinterpret_cast<const float4*>(pb1 + t);
            x2 = *reinterpret_cast<const float4*>(pb2 + t);
        }
    };

    float4 A0, A1, A2;
    loadG(w0idx, A0, A1, A2);

    for (int g = w0idx; g < NGRP; g += NWPB) {
        float4 N0, N1, N2;
        loadG(g + NWPB, N0, N1, N2);   // prefetch next group (4 tiles of cover)

        float ov[4];
        const float Ax[4] = {A0.x, A0.y, A0.z, A0.w};
        const float Ay[4] = {A1.x, A1.y, A1.z, A1.w};
        const float Az[4] = {A2.x, A2.y, A2.z, A2.w};

        #pragma unroll
        for (int k = 0; k < 4; ++k) {
            FragU fh;
            fh.u[0] = pack2(Ax[k], Ay[k]);
            fh.u[1] = pack2(Az[k], c0v);
            fh.u[2] = wc2h;
            fh.u[3] = wc3h;

            f32x16 acc = mfma(wphi, fh, kZero);

            #pragma unroll
            for (int L = 0; L < 3; ++L) {
                f32x16 bAcc = mfma(mk1(biasA[L]), mk1(ones2), kZero);
                FragU p0, p1;
                relu_pack(acc, p0, p1);
                acc = mfma(whi[L][0], p0, bAcc);
                acc = mfma(whi[L][1], p1, acc);
            }

            FragU q0, q1;
            relu_pack(acc, q0, q1);
            f32x16 o = mfma(woF[0], q0, kZero);
            o = mfma(woF[1], q1, o);
            ov[k] = o[0] + bo;
        }

        int t0 = g*128 + row*4;
        if (lane < 32 && t0 + 3 < TLEN) {   // tail cols are exact float4s (40=4x10)
            float4 o4 = make_float4(ov[0], ov[1], ov[2], ov[3]);
            *reinterpret_cast<float4*>(ob + t0) = o4;
        }

        A0 = N0; A1 = N1; A2 = N2;
    }
}

extern "C" void kernel_launch(void* const* d_in, const int* in_sizes, int n_in,
                              void* d_out, int out_size, void* d_ws, size_t ws_size,
                              hipStream_t stream) {
    const float* p     = (const float*)d_in[0];
    // d_in[1] = z (unused by reference)
    const float* c     = (const float*)d_in[2];
    const float* Wproj = (const float*)d_in[3];
    const float* bproj = (const float*)d_in[4];
    const float* Wp    = (const float*)d_in[5];
    const float* bp    = (const float*)d_in[6];
    const float* W0    = (const float*)d_in[7];
    const float* b0    = (const float*)d_in[8];
    const float* W1    = (const float*)d_in[9];
    const float* b1    = (const float*)d_in[10];
    const float* W2    = (const float*)d_in[11];
    const float* b2    = (const float*)d_in[12];
    const float* Wout  = (const float*)d_in[13];
    const float* bout  = (const float*)d_in[14];
    float* out = (float*)d_out;

    dim3 grid(NB*NJ*CHUNKS), block(256);
    ptf_decoder_kernel<<<grid, block, 0, stream>>>(
        p, c, Wproj, bproj, Wp, bp, W0, b0, W1, b1, W2, b2, Wout, bout, out);
}